// Round 1
// baseline (410.871 us; speedup 1.0000x reference)
//
#include <hip/hip_runtime.h>
#include <hip/hip_bf16.h>

// Sizes fixed by the problem.
#define Bz 4
#define Nn 8192
#define Dd 512
#define Ll 64
#define Pp 128
#define Ww 64
#define Ss 32
#define NW 4   // number of window starts per segment

// ---------------------------------------------------------------------------
// zero a float buffer
__global__ void zero_k(float* __restrict__ p, int n) {
    int i = blockIdx.x * 256 + threadIdx.x;
    if (i < n) p[i] = 0.f;
}

// ---------------------------------------------------------------------------
// per-batch coord stats: mean + std(ddof=1)+1e-8 for x and y
__global__ void coordstats_k(const float* __restrict__ coords, float* __restrict__ cstats) {
    int b = blockIdx.x;
    int tid = threadIdx.x;
    double sx = 0, sy = 0, sxx = 0, syy = 0;
    for (int i = tid; i < Nn; i += 256) {
        double x = coords[((size_t)b * Nn + i) * 2 + 0];
        double y = coords[((size_t)b * Nn + i) * 2 + 1];
        sx += x; sy += y; sxx += x * x; syy += y * y;
    }
    for (int o = 32; o > 0; o >>= 1) {
        sx  += __shfl_down(sx,  o); sy  += __shfl_down(sy,  o);
        sxx += __shfl_down(sxx, o); syy += __shfl_down(syy, o);
    }
    __shared__ double red[4][4];
    int wv = tid >> 6, lane = tid & 63;
    if (lane == 0) { red[wv][0] = sx; red[wv][1] = sy; red[wv][2] = sxx; red[wv][3] = syy; }
    __syncthreads();
    if (tid == 0) {
        double tx = 0, ty = 0, txx = 0, tyy = 0;
        for (int i = 0; i < 4; ++i) { tx += red[i][0]; ty += red[i][1]; txx += red[i][2]; tyy += red[i][3]; }
        const double N = (double)Nn;
        double mux = tx / N, muy = ty / N;
        double vx = (txx - N * mux * mux) / (N - 1.0);
        double vy = (tyy - N * muy * muy) / (N - 1.0);
        cstats[b * 4 + 0] = (float)mux;
        cstats[b * 4 + 1] = (float)muy;
        cstats[b * 4 + 2] = (float)sqrt(vx) + 1e-8f;
        cstats[b * 4 + 3] = (float)sqrt(vy) + 1e-8f;
    }
}

// ---------------------------------------------------------------------------
// per-row LayerNorm stats: mu and rs = 1/sqrt(var+1e-5). One wave per row.
__global__ __launch_bounds__(256) void rowstats_k(const float* __restrict__ feats,
                                                  float2* __restrict__ rs, int nrows) {
    int wave = threadIdx.x >> 6, lane = threadIdx.x & 63;
    int row = blockIdx.x * 4 + wave;
    if (row >= nrows) return;
    const float4* fr = (const float4*)(feats + (size_t)row * Dd);
    float s = 0.f, ss = 0.f;
#pragma unroll
    for (int j = 0; j < 2; ++j) {
        float4 v = fr[lane + 64 * j];
        s  += v.x + v.y + v.z + v.w;
        ss += v.x * v.x + v.y * v.y + v.z * v.z + v.w * v.w;
    }
    for (int o = 32; o > 0; o >>= 1) { s += __shfl_down(s, o); ss += __shfl_down(ss, o); }
    if (lane == 0) {
        float mu  = s * (1.f / (float)Dd);
        float var = ss * (1.f / (float)Dd) - mu * mu;
        rs[row] = make_float2(mu, 1.f / sqrtf(var + 1e-5f));
    }
}

// ---------------------------------------------------------------------------
// small tiled GEMM: C[M,N] = A[M,K] * (BT ? B[N,K]^T : B[K,N]) (+ bias[n])
template <int BT, int BIAS>
__global__ __launch_bounds__(256) void gemm32(const float* __restrict__ A,
                                              const float* __restrict__ B,
                                              const float* __restrict__ bias,
                                              float* __restrict__ C,
                                              int M, int N, int K) {
    __shared__ float As[32][33];
    __shared__ float Bs[32][33];
    int tid = threadIdx.x;
    int tx = tid & 31;   // n within tile
    int ty = tid >> 5;   // 0..7
    int n0 = blockIdx.x * 32;
    int m0 = blockIdx.y * 32;
    float acc[4] = {0.f, 0.f, 0.f, 0.f};
    for (int k0 = 0; k0 < K; k0 += 32) {
#pragma unroll
        for (int i = 0; i < 4; ++i) {
            int idx = tid + i * 256;
            int r = idx >> 5, c = idx & 31;
            int m = m0 + r, k = k0 + c;
            As[r][c] = (m < M) ? A[(size_t)m * K + k] : 0.f;
            if (BT) {
                int nn = n0 + r;
                Bs[c][r] = (nn < N) ? B[(size_t)nn * K + k] : 0.f;
            } else {
                int kk = k0 + r, nn = n0 + c;
                Bs[r][c] = (nn < N) ? B[(size_t)kk * N + nn] : 0.f;
            }
        }
        __syncthreads();
#pragma unroll
        for (int kk = 0; kk < 32; ++kk) {
            float bv = Bs[kk][tx];
#pragma unroll
            for (int i = 0; i < 4; ++i)
                acc[i] = fmaf(As[ty + 8 * i][kk], bv, acc[i]);
        }
        __syncthreads();
    }
#pragma unroll
    for (int i = 0; i < 4; ++i) {
        int m = m0 + ty + 8 * i, nn = n0 + tx;
        if (m < M && nn < N)
            C[(size_t)m * N + nn] = acc[i] + (BIAS ? bias[nn] : 0.f);
    }
}

// ---------------------------------------------------------------------------
// sqk[l] = sum_d QK[l,d]; qb2[l] = sum_e Q[l,e]*b2[e]
__global__ void sqk_k(const float* __restrict__ QK, const float* __restrict__ Q,
                      const float* __restrict__ b2, float* __restrict__ sqk,
                      float* __restrict__ qb2) {
    int l = blockIdx.x, lane = threadIdx.x; // 64 threads
    float s1 = 0.f, s2 = 0.f;
#pragma unroll
    for (int j = 0; j < 8; ++j) {
        int d = lane + 64 * j;
        s1 += QK[l * Dd + d];
        s2 += Q[l * Dd + d] * b2[d];
    }
    for (int o = 32; o > 0; o >>= 1) { s1 += __shfl_down(s1, o); s2 += __shfl_down(s2, o); }
    if (lane == 0) { sqk[l] = s1; qb2[l] = s2; }
}

// ---------------------------------------------------------------------------
// main windowed-attention kernel. One block per (b, l, n-window).
__global__ __launch_bounds__(256) void attn_win(
    const float* __restrict__ feats, const float* __restrict__ coords,
    const float* __restrict__ cstats, const float2* __restrict__ rowst,
    const float* __restrict__ QKm, const float* __restrict__ Gm,
    const float* __restrict__ sqk, const float* __restrict__ qb2,
    const float* __restrict__ W1, const float* __restrict__ b1,
    float* __restrict__ fmean) {
    __shared__ float qk_s[Dd], g_s[Dd], w1a[Dd], w1b[Dd], b1s[Dd];
    __shared__ float sx[Ww], sy[Ww], smu[Ww], srs[Ww], sar[Ww], slog[Ww];
    __shared__ int srow[Ww];
    __shared__ float red[4];

    int bx = blockIdx.x;
    int n = bx & 3, l = (bx >> 2) & 63, b = bx >> 8;
    int tid = threadIdx.x;
    int nvalid = min(Ww, Pp - n * Ss);   // {64,64,64,32}

    for (int i = tid; i < Dd; i += 256) {
        qk_s[i] = QKm[l * Dd + i];
        g_s[i]  = Gm[l * Dd + i];
        w1a[i]  = W1[2 * i];
        w1b[i]  = W1[2 * i + 1];
        b1s[i]  = b1[i];
    }
    if (tid < Ww) {
        int w = tid;
        int p = n * Ss + w;
        bool val = p < Pp;
        int row = b * Nn + l * Pp + (val ? p : Pp - 1);
        srow[w] = row;
        float cx = 0.f, cy = 0.f;
        if (val) {
            float x = coords[(size_t)row * 2], y = coords[(size_t)row * 2 + 1];
            cx = (x - cstats[b * 4 + 0]) / cstats[b * 4 + 2];
            cy = (y - cstats[b * 4 + 1]) / cstats[b * 4 + 3];
        }
        sx[w] = cx; sy[w] = cy;
        float2 st = rowst[row];
        smu[w] = st.x; srs[w] = st.y;
        float a1 = cx, a2 = cy;
        for (int o = 32; o > 0; o >>= 1) { a1 += __shfl_down(a1, o); a2 += __shfl_down(a2, o); }
        if (w == 0) { red[0] = a1 / (float)nvalid; red[1] = a2 / (float)nvalid; }
    }
    __syncthreads();
    float cmx = red[0], cmy = red[1];
    float sqk_l = sqk[l], qb2_l = qb2[l];
    const float invtemp = 0.04419417382415922f; // 1/sqrt(512)
    int wv = tid >> 6, lane = tid & 63;
    // phase 1: logits. wave wv handles w = wv*16 .. wv*16+15
    for (int wi = 0; wi < 16; ++wi) {
        int w = wv * 16 + wi;
        if (w < nvalid) {
            const float* fr = feats + (size_t)srow[w] * Dd;
            float px = sx[w] - cmx, py = sy[w] - cmy;
            float a = 0.f, hs = 0.f;
#pragma unroll
            for (int j = 0; j < 8; ++j) {
                int d = lane + 64 * j;
                a = fmaf(qk_s[d], fr[d], a);
                float hv = fmaf(w1a[d], px, fmaf(w1b[d], py, b1s[d]));
                hs = fmaf(g_s[d], fmaxf(hv, 0.f), hs);
            }
            for (int o = 32; o > 0; o >>= 1) { a += __shfl_down(a, o); hs += __shfl_down(hs, o); }
            if (lane == 0) {
                float lg = (srs[w] * (a - smu[w] * sqk_l) + hs + qb2_l) * invtemp;
                slog[w] = fminf(fmaxf(lg, -10.f), 10.f);
            }
        }
    }
    __syncthreads();
    // phase 2: softmax across the 64 window slots (wave 0)
    if (tid < Ww) {
        int w = tid;
        float lg = (w < nvalid) ? slog[w] : -1e30f;
        float m = lg;
        for (int o = 32; o > 0; o >>= 1) m = fmaxf(m, __shfl_xor(m, o));
        float e = (w < nvalid) ? expf(lg - m) : 0.f;
        float s = e;
        for (int o = 32; o > 0; o >>= 1) s += __shfl_xor(s, o);
        float at = e / s;
        float ar = at * srs[w];
        sar[w] = ar;
        float t2 = ar * smu[w];
        for (int o = 32; o > 0; o >>= 1) t2 += __shfl_xor(t2, o);
        if (w == 0) red[2] = t2;
    }
    __syncthreads();
    float S2 = red[2];
    // phase 3: fbar_d = sum_w ar_w * f[row_w, d]  -  S2 ; accumulate mean over n
    float acc0 = 0.f, acc1 = 0.f;
    int d0 = tid, d1 = tid + 256;
    for (int w = 0; w < nvalid; ++w) {
        const float* fr = feats + (size_t)srow[w] * Dd;
        float ar = sar[w];
        acc0 = fmaf(ar, fr[d0], acc0);
        acc1 = fmaf(ar, fr[d1], acc1);
    }
    float* fm = fmean + ((size_t)(b * Ll + l)) * Dd;
    atomicAdd(fm + d0, 0.25f * (acc0 - S2));
    atomicAdd(fm + d1, 0.25f * (acc1 - S2));
}

// ---------------------------------------------------------------------------
extern "C" void kernel_launch(void* const* d_in, const int* in_sizes, int n_in,
                              void* d_out, int out_size, void* d_ws, size_t ws_size,
                              hipStream_t stream) {
    const float* feats  = (const float*)d_in[0];
    const float* coords = (const float*)d_in[1];
    // d_in[2] = mask, unused (all false, and unused by the reference body)
    const float* z  = (const float*)d_in[3];
    const float* Wq = (const float*)d_in[4];
    const float* Wk = (const float*)d_in[5];
    const float* Wv = (const float*)d_in[6];
    const float* W1 = (const float*)d_in[7];
    const float* b1 = (const float*)d_in[8];
    const float* W2 = (const float*)d_in[9];
    const float* b2 = (const float*)d_in[10];
    const float* Wo = (const float*)d_in[11];
    const float* bo = (const float*)d_in[12];
    float* out = (float*)d_out;

    // workspace layout (floats)
    float* ws = (float*)d_ws;
    float*  cstats = ws;                        // 16
    float2* rowst  = (float2*)(ws + 16);        // Bz*Nn float2 = 65536 floats
    float*  Q      = ws + 16 + 2 * Bz * Nn;     // 64*512
    float*  QK     = Q + Ll * Dd;
    float*  G      = QK + Ll * Dd;
    float*  sqk    = G + Ll * Dd;               // 64
    float*  qb2    = sqk + Ll;                  // 64
    float*  fmean  = qb2 + Ll;                  // 256*512
    float*  zl     = fmean + Bz * Ll * Dd;      // 256*512

    const int nFmean = Bz * Ll * Dd;            // 131072

    zero_k<<<(nFmean + 255) / 256, 256, 0, stream>>>(fmean, nFmean);
    coordstats_k<<<Bz, 256, 0, stream>>>(coords, cstats);
    rowstats_k<<<(Bz * Nn) / 4, 256, 0, stream>>>(feats, rowst, Bz * Nn);

    // Q = z @ Wq^T  (64x512)
    gemm32<1, 0><<<dim3(Dd / 32, Ll / 32), 256, 0, stream>>>(z, Wq, nullptr, Q, Ll, Dd, Dd);
    // QK = Q @ Wk ; G = Q @ W2   (64x512 each)
    gemm32<0, 0><<<dim3(Dd / 32, Ll / 32), 256, 0, stream>>>(Q, Wk, nullptr, QK, Ll, Dd, Dd);
    gemm32<0, 0><<<dim3(Dd / 32, Ll / 32), 256, 0, stream>>>(Q, W2, nullptr, G, Ll, Dd, Dd);
    sqk_k<<<Ll, 64, 0, stream>>>(QK, Q, b2, sqk, qb2);

    attn_win<<<Bz * Ll * NW, 256, 0, stream>>>(feats, coords, cstats, rowst,
                                               QK, G, sqk, qb2, W1, b1, fmean);

    // zl = fmean @ Wv^T ; out = zl @ Wo^T + bo   (256x512 each)
    gemm32<1, 0><<<dim3(Dd / 32, (Bz * Ll) / 32), 256, 0, stream>>>(fmean, Wv, nullptr, zl,
                                                                    Bz * Ll, Dd, Dd);
    gemm32<1, 1><<<dim3(Dd / 32, (Bz * Ll) / 32), 256, 0, stream>>>(zl, Wo, bo, out,
                                                                    Bz * Ll, Dd, Dd);
}

// Round 2
// 240.718 us; speedup vs baseline: 1.7069x; 1.7069x over previous
//
#include <hip/hip_runtime.h>
#include <hip/hip_bf16.h>

// Sizes fixed by the problem.
#define Bz 4
#define Nn 8192
#define Dd 512
#define Ll 64
#define Pp 128
#define Ww 64
#define Ss 32
#define NW 4   // number of window starts per segment

// ---------------------------------------------------------------------------
// fused init: zero the accumulator region, seed out with bias
__global__ __launch_bounds__(256) void init_k(float* __restrict__ zbase, int nzero,
                                              float* __restrict__ out,
                                              const float* __restrict__ bo) {
    int i = blockIdx.x * 256 + threadIdx.x;
    if (i < nzero) zbase[i] = 0.f;
    if (i < Bz * Ll * Dd) out[i] = bo[i & (Dd - 1)];
}

// ---------------------------------------------------------------------------
// per-batch coord stats: mean + std(ddof=1)+1e-8 for x and y
__global__ void coordstats_k(const float* __restrict__ coords, float* __restrict__ cstats) {
    int b = blockIdx.x;
    int tid = threadIdx.x;
    double sx = 0, sy = 0, sxx = 0, syy = 0;
    for (int i = tid; i < Nn; i += 256) {
        double x = coords[((size_t)b * Nn + i) * 2 + 0];
        double y = coords[((size_t)b * Nn + i) * 2 + 1];
        sx += x; sy += y; sxx += x * x; syy += y * y;
    }
    for (int o = 32; o > 0; o >>= 1) {
        sx  += __shfl_down(sx,  o); sy  += __shfl_down(sy,  o);
        sxx += __shfl_down(sxx, o); syy += __shfl_down(syy, o);
    }
    __shared__ double red[4][4];
    int wv = tid >> 6, lane = tid & 63;
    if (lane == 0) { red[wv][0] = sx; red[wv][1] = sy; red[wv][2] = sxx; red[wv][3] = syy; }
    __syncthreads();
    if (tid == 0) {
        double tx = 0, ty = 0, txx = 0, tyy = 0;
        for (int i = 0; i < 4; ++i) { tx += red[i][0]; ty += red[i][1]; txx += red[i][2]; tyy += red[i][3]; }
        const double N = (double)Nn;
        double mux = tx / N, muy = ty / N;
        double vx = (txx - N * mux * mux) / (N - 1.0);
        double vy = (tyy - N * muy * muy) / (N - 1.0);
        cstats[b * 4 + 0] = (float)mux;
        cstats[b * 4 + 1] = (float)muy;
        cstats[b * 4 + 2] = (float)sqrt(vx) + 1e-8f;
        cstats[b * 4 + 3] = (float)sqrt(vy) + 1e-8f;
    }
}

// ---------------------------------------------------------------------------
// per-row LayerNorm stats: mu and rs = 1/sqrt(var+1e-5). One wave per row.
__global__ __launch_bounds__(256) void rowstats_k(const float* __restrict__ feats,
                                                  float2* __restrict__ rs, int nrows) {
    int wave = threadIdx.x >> 6, lane = threadIdx.x & 63;
    int row = blockIdx.x * 4 + wave;
    if (row >= nrows) return;
    const float4* fr = (const float4*)(feats + (size_t)row * Dd);
    float s = 0.f, ss = 0.f;
#pragma unroll
    for (int j = 0; j < 2; ++j) {
        float4 v = fr[lane + 64 * j];
        s  += v.x + v.y + v.z + v.w;
        ss += v.x * v.x + v.y * v.y + v.z * v.z + v.w * v.w;
    }
    for (int o = 32; o > 0; o >>= 1) { s += __shfl_down(s, o); ss += __shfl_down(ss, o); }
    if (lane == 0) {
        float mu  = s * (1.f / (float)Dd);
        float var = ss * (1.f / (float)Dd) - mu * mu;
        rs[row] = make_float2(mu, 1.f / sqrtf(var + 1e-5f));
    }
}

// ---------------------------------------------------------------------------
// Split-K one-shot GEMM tile. C(M x N) += A(M x K) * op(B). BT=1: B[N,K] (C=A*B^T),
// BT=0: B[K,N]. Grid: (N/32, M/64, KZ or 2*KZ). Each block loads its whole
// 64x64 A chunk + B chunk in ONE round of float4 loads (one latency exposure),
// computes a 64x32 partial, atomicAdds into C. Optional dual-B: blocks with
// blockIdx.z >= KZ use B2/C2 (same BT). Optional fused row-sum epilogue for the
// B1 half: rs_out[m] += sum_n partial[m,n]*rs_scale[n] (scale null -> 1).
template <int BT>
__global__ __launch_bounds__(256) void gemmsk(
    const float* __restrict__ A,
    const float* __restrict__ B1, float* __restrict__ C1,
    const float* __restrict__ B2, float* __restrict__ C2,
    const float* __restrict__ rs_scale, float* __restrict__ rs_out,
    int N, int K, int KZ) {
    __shared__ float As[64][68];
    __shared__ float Bs[64][36];
    int tid = threadIdx.x;
    int n0 = blockIdx.x * 32;
    int m0 = blockIdx.y * 64;
    int kz = blockIdx.z;
    const float* B = B1; float* C = C1; float* rso = rs_out;
    if (kz >= KZ) { kz -= KZ; B = B2; C = C2; rso = nullptr; }
    int k0 = kz * 64;

    // A tile: 64 rows x 64 cols, float4 loads
    {
        int r = tid >> 4, c4 = (tid & 15) * 4;
#pragma unroll
        for (int i = 0; i < 4; ++i) {
            const float4 v = *(const float4*)&A[(size_t)(m0 + r + 16 * i) * K + k0 + c4];
            *(float4*)&As[r + 16 * i][c4] = v;
        }
    }
    if (BT) {
        // B[n, k]: 32 rows x 64 cols -> Bs[k][n]
        int nr = tid >> 4, c4 = (tid & 15) * 4;
#pragma unroll
        for (int i = 0; i < 2; ++i) {
            int nn = nr + 16 * i;
            const float4 v = *(const float4*)&B[(size_t)(n0 + nn) * K + k0 + c4];
            Bs[c4 + 0][nn] = v.x; Bs[c4 + 1][nn] = v.y;
            Bs[c4 + 2][nn] = v.z; Bs[c4 + 3][nn] = v.w;
        }
    } else {
        // B[k, n]: 64 rows x 32 cols -> Bs[k][n]
        int kr = tid >> 3, c4 = (tid & 7) * 4;
#pragma unroll
        for (int i = 0; i < 2; ++i) {
            int kk = kr + 32 * i;
            const float4 v = *(const float4*)&B[(size_t)(k0 + kk) * N + n0 + c4];
            *(float4*)&Bs[kk][c4] = v;
        }
    }
    __syncthreads();
    int tx = tid & 31, ty = tid >> 5;
    float acc[8] = {0.f, 0.f, 0.f, 0.f, 0.f, 0.f, 0.f, 0.f};
#pragma unroll 16
    for (int kk = 0; kk < 64; ++kk) {
        float bv = Bs[kk][tx];
#pragma unroll
        for (int i = 0; i < 8; ++i)
            acc[i] = fmaf(As[ty + 8 * i][kk], bv, acc[i]);
    }
#pragma unroll
    for (int i = 0; i < 8; ++i)
        atomicAdd(&C[(size_t)(m0 + ty + 8 * i) * N + n0 + tx], acc[i]);
    if (rso != nullptr) {
        float sc = (rs_scale != nullptr) ? rs_scale[n0 + tx] : 1.0f;
#pragma unroll
        for (int i = 0; i < 8; ++i) {
            float v = acc[i] * sc;
            for (int o = 16; o > 0; o >>= 1) v += __shfl_xor(v, o);
            if (tx == 0) atomicAdd(&rso[m0 + ty + 8 * i], v);
        }
    }
}

// ---------------------------------------------------------------------------
// main windowed-attention kernel. One block per (b, l, n-window).
__global__ __launch_bounds__(256) void attn_win(
    const float* __restrict__ feats, const float* __restrict__ coords,
    const float* __restrict__ cstats, const float2* __restrict__ rowst,
    const float* __restrict__ QKm, const float* __restrict__ Gm,
    const float* __restrict__ sqk, const float* __restrict__ qb2,
    const float* __restrict__ W1, const float* __restrict__ b1,
    float* __restrict__ fmean) {
    __shared__ float qk_s[Dd], g_s[Dd], w1a[Dd], w1b[Dd], b1s[Dd];
    __shared__ float sx[Ww], sy[Ww], smu[Ww], srs[Ww], sar[Ww], slog[Ww];
    __shared__ int srow[Ww];
    __shared__ float red[4];

    int bx = blockIdx.x;
    int n = bx & 3, l = (bx >> 2) & 63, b = bx >> 8;
    int tid = threadIdx.x;
    int nvalid = min(Ww, Pp - n * Ss);   // {64,64,64,32}

    for (int i = tid; i < Dd; i += 256) {
        qk_s[i] = QKm[l * Dd + i];
        g_s[i]  = Gm[l * Dd + i];
        w1a[i]  = W1[2 * i];
        w1b[i]  = W1[2 * i + 1];
        b1s[i]  = b1[i];
    }
    if (tid < Ww) {
        int w = tid;
        int p = n * Ss + w;
        bool val = p < Pp;
        int row = b * Nn + l * Pp + (val ? p : Pp - 1);
        srow[w] = row;
        float cx = 0.f, cy = 0.f;
        if (val) {
            float x = coords[(size_t)row * 2], y = coords[(size_t)row * 2 + 1];
            cx = (x - cstats[b * 4 + 0]) / cstats[b * 4 + 2];
            cy = (y - cstats[b * 4 + 1]) / cstats[b * 4 + 3];
        }
        sx[w] = cx; sy[w] = cy;
        float2 st = rowst[row];
        smu[w] = st.x; srs[w] = st.y;
        float a1 = cx, a2 = cy;
        for (int o = 32; o > 0; o >>= 1) { a1 += __shfl_down(a1, o); a2 += __shfl_down(a2, o); }
        if (w == 0) { red[0] = a1 / (float)nvalid; red[1] = a2 / (float)nvalid; }
    }
    __syncthreads();
    float cmx = red[0], cmy = red[1];
    float sqk_l = sqk[l], qb2_l = qb2[l];
    const float invtemp = 0.04419417382415922f; // 1/sqrt(512)
    int wv = tid >> 6, lane = tid & 63;
    // phase 1: logits. wave wv handles w = wv*16 .. wv*16+15
    for (int wi = 0; wi < 16; ++wi) {
        int w = wv * 16 + wi;
        if (w < nvalid) {
            const float* fr = feats + (size_t)srow[w] * Dd;
            float px = sx[w] - cmx, py = sy[w] - cmy;
            float a = 0.f, hs = 0.f;
#pragma unroll
            for (int j = 0; j < 8; ++j) {
                int d = lane + 64 * j;
                a = fmaf(qk_s[d], fr[d], a);
                float hv = fmaf(w1a[d], px, fmaf(w1b[d], py, b1s[d]));
                hs = fmaf(g_s[d], fmaxf(hv, 0.f), hs);
            }
            for (int o = 32; o > 0; o >>= 1) { a += __shfl_down(a, o); hs += __shfl_down(hs, o); }
            if (lane == 0) {
                float lg = (srs[w] * (a - smu[w] * sqk_l) + hs + qb2_l) * invtemp;
                slog[w] = fminf(fmaxf(lg, -10.f), 10.f);
            }
        }
    }
    __syncthreads();
    // phase 2: softmax across the 64 window slots (wave 0)
    if (tid < Ww) {
        int w = tid;
        float lg = (w < nvalid) ? slog[w] : -1e30f;
        float m = lg;
        for (int o = 32; o > 0; o >>= 1) m = fmaxf(m, __shfl_xor(m, o));
        float e = (w < nvalid) ? expf(lg - m) : 0.f;
        float s = e;
        for (int o = 32; o > 0; o >>= 1) s += __shfl_xor(s, o);
        float at = e / s;
        float ar = at * srs[w];
        sar[w] = ar;
        float t2 = ar * smu[w];
        for (int o = 32; o > 0; o >>= 1) t2 += __shfl_xor(t2, o);
        if (w == 0) red[2] = t2;
    }
    __syncthreads();
    float S2 = red[2];
    // phase 3: fbar_d = sum_w ar_w * f[row_w, d]  -  S2 ; accumulate mean over n
    float acc0 = 0.f, acc1 = 0.f;
    int d0 = tid, d1 = tid + 256;
    for (int w = 0; w < nvalid; ++w) {
        const float* fr = feats + (size_t)srow[w] * Dd;
        float ar = sar[w];
        acc0 = fmaf(ar, fr[d0], acc0);
        acc1 = fmaf(ar, fr[d1], acc1);
    }
    float* fm = fmean + ((size_t)(b * Ll + l)) * Dd;
    atomicAdd(fm + d0, 0.25f * (acc0 - S2));
    atomicAdd(fm + d1, 0.25f * (acc1 - S2));
}

// ---------------------------------------------------------------------------
extern "C" void kernel_launch(void* const* d_in, const int* in_sizes, int n_in,
                              void* d_out, int out_size, void* d_ws, size_t ws_size,
                              hipStream_t stream) {
    const float* feats  = (const float*)d_in[0];
    const float* coords = (const float*)d_in[1];
    // d_in[2] = mask, unused (all false, and unused by the reference body)
    const float* z  = (const float*)d_in[3];
    const float* Wq = (const float*)d_in[4];
    const float* Wk = (const float*)d_in[5];
    const float* Wv = (const float*)d_in[6];
    const float* W1 = (const float*)d_in[7];
    const float* b1 = (const float*)d_in[8];
    const float* W2 = (const float*)d_in[9];
    const float* b2 = (const float*)d_in[10];
    const float* Wo = (const float*)d_in[11];
    const float* bo = (const float*)d_in[12];
    float* out = (float*)d_out;

    // workspace layout (floats)
    float* ws = (float*)d_ws;
    float*  cstats = ws;                        // 16
    float2* rowst  = (float2*)(ws + 16);        // Bz*Nn float2 = 65536 floats
    // ---- zero-initialized accumulator region starts here ----
    float*  zbase  = ws + 16 + 2 * Bz * Nn;
    float*  Q      = zbase;                     // 64*512
    float*  QK     = Q + Ll * Dd;               // 64*512
    float*  G      = QK + Ll * Dd;              // 64*512
    float*  sqk    = G + Ll * Dd;               // 64
    float*  qb2    = sqk + Ll;                  // 64
    float*  fmean  = qb2 + Ll;                  // 256*512
    float*  zl     = fmean + Bz * Ll * Dd;      // 256*512
    const int nzero = 3 * Ll * Dd + 2 * Ll + 2 * Bz * Ll * Dd;  // 360576

    init_k<<<(nzero + 255) / 256, 256, 0, stream>>>(zbase, nzero, out, bo);
    coordstats_k<<<Bz, 256, 0, stream>>>(coords, cstats);
    rowstats_k<<<(Bz * Nn) / 4, 256, 0, stream>>>(feats, rowst, Bz * Nn);

    // Q = z @ Wq^T (split-K, 128 blocks); epilogue: qb2[l] = sum_e Q[l,e]*b2[e]
    gemmsk<1><<<dim3(Dd / 32, Ll / 64, 8), 256, 0, stream>>>(
        z, Wq, Q, nullptr, nullptr, b2, qb2, Dd, Dd, 8);
    // QK = Q @ Wk and G = Q @ W2 fused (256 blocks); epilogue: sqk[l] = sum_d QK[l,d]
    gemmsk<0><<<dim3(Dd / 32, Ll / 64, 16), 256, 0, stream>>>(
        Q, Wk, QK, W2, G, nullptr, sqk, Dd, Dd, 8);

    attn_win<<<Bz * Ll * NW, 256, 0, stream>>>(feats, coords, cstats, rowst,
                                               QK, G, sqk, qb2, W1, b1, fmean);

    // zl = fmean @ Wv^T ; out = bias + zl @ Wo^T   (512 blocks each)
    gemmsk<1><<<dim3(Dd / 32, (Bz * Ll) / 64, 8), 256, 0, stream>>>(
        fmean, Wv, zl, nullptr, nullptr, nullptr, nullptr, Dd, Dd, 8);
    gemmsk<1><<<dim3(Dd / 32, (Bz * Ll) / 64, 8), 256, 0, stream>>>(
        zl, Wo, out, nullptr, nullptr, nullptr, nullptr, Dd, Dd, 8);
}

// Round 3
// 216.407 us; speedup vs baseline: 1.8986x; 1.1123x over previous
//
#include <hip/hip_runtime.h>
#include <hip/hip_bf16.h>

// Sizes fixed by the problem.
#define Bz 4
#define Nn 8192
#define Dd 512
#define Ll 64
#define Pp 128
#define Ww 64
#define Ss 32
#define NW 4   // number of window starts per segment

// ---------------------------------------------------------------------------
// fused init: zero the accumulator region (Q/QK/G/sqk/qb2/zl), seed out with bias
__global__ __launch_bounds__(256) void init_k(float* __restrict__ zbase, int nzero,
                                              float* __restrict__ out,
                                              const float* __restrict__ bo) {
    int i = blockIdx.x * 256 + threadIdx.x;
    if (i < nzero) zbase[i] = 0.f;
    if (i < Bz * Ll * Dd) out[i] = bo[i & (Dd - 1)];
}

// ---------------------------------------------------------------------------
// per-batch coord stats: mean + std(ddof=1)+1e-8 for x and y. 1024 threads.
__global__ __launch_bounds__(1024) void coordstats_k(const float* __restrict__ coords,
                                                     float* __restrict__ cstats) {
    int b = blockIdx.x;
    int tid = threadIdx.x;
    double sx = 0, sy = 0, sxx = 0, syy = 0;
    for (int i = tid; i < Nn; i += 1024) {
        double x = coords[((size_t)b * Nn + i) * 2 + 0];
        double y = coords[((size_t)b * Nn + i) * 2 + 1];
        sx += x; sy += y; sxx += x * x; syy += y * y;
    }
    for (int o = 32; o > 0; o >>= 1) {
        sx  += __shfl_down(sx,  o); sy  += __shfl_down(sy,  o);
        sxx += __shfl_down(sxx, o); syy += __shfl_down(syy, o);
    }
    __shared__ double red[16][4];
    int wv = tid >> 6, lane = tid & 63;
    if (lane == 0) { red[wv][0] = sx; red[wv][1] = sy; red[wv][2] = sxx; red[wv][3] = syy; }
    __syncthreads();
    if (tid == 0) {
        double tx = 0, ty = 0, txx = 0, tyy = 0;
        for (int i = 0; i < 16; ++i) { tx += red[i][0]; ty += red[i][1]; txx += red[i][2]; tyy += red[i][3]; }
        const double N = (double)Nn;
        double mux = tx / N, muy = ty / N;
        double vx = (txx - N * mux * mux) / (N - 1.0);
        double vy = (tyy - N * muy * muy) / (N - 1.0);
        cstats[b * 4 + 0] = (float)mux;
        cstats[b * 4 + 1] = (float)muy;
        cstats[b * 4 + 2] = (float)sqrt(vx) + 1e-8f;
        cstats[b * 4 + 3] = (float)sqrt(vy) + 1e-8f;
    }
}

// ---------------------------------------------------------------------------
// Split-K one-shot GEMM tile (unchanged from R2; each block: one load round,
// 64x32 partial, atomicAdd). Optional dual-B and fused row-sum epilogue.
template <int BT>
__global__ __launch_bounds__(256) void gemmsk(
    const float* __restrict__ A,
    const float* __restrict__ B1, float* __restrict__ C1,
    const float* __restrict__ B2, float* __restrict__ C2,
    const float* __restrict__ rs_scale, float* __restrict__ rs_out,
    int N, int K, int KZ) {
    __shared__ float As[64][68];
    __shared__ float Bs[64][36];
    int tid = threadIdx.x;
    int n0 = blockIdx.x * 32;
    int m0 = blockIdx.y * 64;
    int kz = blockIdx.z;
    const float* B = B1; float* C = C1; float* rso = rs_out;
    if (kz >= KZ) { kz -= KZ; B = B2; C = C2; rso = nullptr; }
    int k0 = kz * 64;
    {
        int r = tid >> 4, c4 = (tid & 15) * 4;
#pragma unroll
        for (int i = 0; i < 4; ++i) {
            const float4 v = *(const float4*)&A[(size_t)(m0 + r + 16 * i) * K + k0 + c4];
            *(float4*)&As[r + 16 * i][c4] = v;
        }
    }
    if (BT) {
        int nr = tid >> 4, c4 = (tid & 15) * 4;
#pragma unroll
        for (int i = 0; i < 2; ++i) {
            int nn = nr + 16 * i;
            const float4 v = *(const float4*)&B[(size_t)(n0 + nn) * K + k0 + c4];
            Bs[c4 + 0][nn] = v.x; Bs[c4 + 1][nn] = v.y;
            Bs[c4 + 2][nn] = v.z; Bs[c4 + 3][nn] = v.w;
        }
    } else {
        int kr = tid >> 3, c4 = (tid & 7) * 4;
#pragma unroll
        for (int i = 0; i < 2; ++i) {
            int kk = kr + 32 * i;
            const float4 v = *(const float4*)&B[(size_t)(k0 + kk) * N + n0 + c4];
            *(float4*)&Bs[kk][c4] = v;
        }
    }
    __syncthreads();
    int tx = tid & 31, ty = tid >> 5;
    float acc[8] = {0.f, 0.f, 0.f, 0.f, 0.f, 0.f, 0.f, 0.f};
#pragma unroll 16
    for (int kk = 0; kk < 64; ++kk) {
        float bv = Bs[kk][tx];
#pragma unroll
        for (int i = 0; i < 8; ++i)
            acc[i] = fmaf(As[ty + 8 * i][kk], bv, acc[i]);
    }
#pragma unroll
    for (int i = 0; i < 8; ++i)
        atomicAdd(&C[(size_t)(m0 + ty + 8 * i) * N + n0 + tx], acc[i]);
    if (rso != nullptr) {
        float sc = (rs_scale != nullptr) ? rs_scale[n0 + tx] : 1.0f;
#pragma unroll
        for (int i = 0; i < 8; ++i) {
            float v = acc[i] * sc;
            for (int o = 16; o > 0; o >>= 1) v += __shfl_xor(v, o);
            if (tx == 0) atomicAdd(&rso[m0 + ty + 8 * i], v);
        }
    }
}

// ---------------------------------------------------------------------------
// Fused attention: one block per (b,l). Pass 1 over the segment's 128 rows
// computes per-row (mu, rs, a=QK.f) — absorbs rowstats. Middle: per-window
// pos-bias + softmax from LDS scalars. Pass 2: single combined weighted
// feature sum (windows' weights merged per row), direct store (no atomics).
__global__ __launch_bounds__(512) void attn2(
    const float* __restrict__ feats, const float* __restrict__ coords,
    const float* __restrict__ cstats,
    const float* __restrict__ QKm, const float* __restrict__ Gm,
    const float* __restrict__ sqk, const float* __restrict__ qb2,
    const float* __restrict__ W1, const float* __restrict__ b1,
    float* __restrict__ fmean) {
    __shared__ float  qk_s[Dd];
    __shared__ float4 wpack[Dd];            // {w1a, w1b, b1, g}
    __shared__ float  scx[Pp], scy[Pp];
    __shared__ float  smu[Pp], srs[Pp], sa[Pp];
    __shared__ float  shs[NW * Ww];
    __shared__ float  sar[NW][Ww];
    __shared__ float  swt[Pp];
    __shared__ float  scm[8];               // cmx[4], cmy[4]
    __shared__ float  s2red[NW];
    __shared__ float  soff;
    __shared__ float  spart[4][Dd];

    int bx = blockIdx.x;                    // b*64 + l
    int l = bx & 63, b = bx >> 6;
    int tid = threadIdx.x;
    int wv = tid >> 6, lane = tid & 63;

    // ---- prologue ----
    qk_s[tid]  = QKm[l * Dd + tid];
    wpack[tid] = make_float4(W1[2 * tid], W1[2 * tid + 1], b1[tid], Gm[l * Dd + tid]);
    if (tid < Pp) {
        int row = bx * Pp + tid;
        float x = coords[(size_t)row * 2], y = coords[(size_t)row * 2 + 1];
        scx[tid] = (x - cstats[b * 4 + 0]) / cstats[b * 4 + 2];
        scy[tid] = (y - cstats[b * 4 + 1]) / cstats[b * 4 + 3];
    }
    float sqk_l = sqk[l], qb2_l = qb2[l];
    __syncthreads();

    // window coord means (waves 0..3)
    if (wv < 4) {
        int n = wv, w = lane;
        int nv = (n == 3) ? 32 : 64;
        float cx = (w < nv) ? scx[n * Ss + w] : 0.f;
        float cy = (w < nv) ? scy[n * Ss + w] : 0.f;
        for (int o = 32; o > 0; o >>= 1) { cx += __shfl_xor(cx, o); cy += __shfl_xor(cy, o); }
        if (lane == 0) { scm[n] = cx / (float)nv; scm[4 + n] = cy / (float)nv; }
    }

    // ---- pass 1: per-row mu, rs, a (one HBM pass over 128 rows) ----
    const float* fbase = feats + (size_t)bx * Pp * Dd;
    float4 q0 = ((const float4*)qk_s)[lane];
    float4 q1 = ((const float4*)qk_s)[lane + 64];
#pragma unroll 2
    for (int i = 0; i < 16; ++i) {
        int r = wv * 16 + i;
        const float4* fr = (const float4*)(fbase + (size_t)r * Dd);
        float4 v0 = fr[lane];
        float4 v1 = fr[lane + 64];
        float s  = v0.x + v0.y + v0.z + v0.w + v1.x + v1.y + v1.z + v1.w;
        float ss = v0.x * v0.x + v0.y * v0.y + v0.z * v0.z + v0.w * v0.w
                 + v1.x * v1.x + v1.y * v1.y + v1.z * v1.z + v1.w * v1.w;
        float a  = v0.x * q0.x + v0.y * q0.y + v0.z * q0.z + v0.w * q0.w
                 + v1.x * q1.x + v1.y * q1.y + v1.z * q1.z + v1.w * q1.w;
        for (int o = 32; o > 0; o >>= 1) {
            s += __shfl_xor(s, o); ss += __shfl_xor(ss, o); a += __shfl_xor(a, o);
        }
        if (lane == 0) {
            float mu  = s * (1.f / (float)Dd);
            float var = ss * (1.f / (float)Dd) - mu * mu;
            smu[r] = mu; srs[r] = 1.f / sqrtf(var + 1e-5f); sa[r] = a;
        }
    }
    __syncthreads();

    // ---- pos-bias hs per (window, slot): 2 lanes per slot, half-D each ----
    {
        int s = tid >> 1, half = tid & 1;
        int n = s >> 6, w = s & 63;
        int nv = (n == 3) ? 32 : 64;
        float hs = 0.f;
        if (w < nv) {
            int p = n * Ss + w;
            float px = scx[p] - scm[n], py = scy[p] - scm[4 + n];
            int d0 = half * 256;
#pragma unroll 4
            for (int d = d0; d < d0 + 256; ++d) {
                float4 c = wpack[d];
                hs = fmaf(c.w, fmaxf(fmaf(c.x, px, fmaf(c.y, py, c.z)), 0.f), hs);
            }
        }
        hs += __shfl_xor(hs, 1);
        if (half == 0) shs[s] = hs;
    }
    __syncthreads();

    // ---- softmax per window (waves 0..3) ----
    const float invtemp = 0.04419417382415922f; // 1/sqrt(512)
    if (wv < 4) {
        int n = wv, w = lane;
        int nv = (n == 3) ? 32 : 64;
        int p = n * Ss + ((w < nv) ? w : 0);
        float lg = -1e30f;
        if (w < nv) {
            lg = (srs[p] * (sa[p] - smu[p] * sqk_l) + shs[n * Ww + w] + qb2_l) * invtemp;
            lg = fminf(fmaxf(lg, -10.f), 10.f);
        }
        float m = lg;
        for (int o = 32; o > 0; o >>= 1) m = fmaxf(m, __shfl_xor(m, o));
        float e = (w < nv) ? expf(lg - m) : 0.f;
        float ssum = e;
        for (int o = 32; o > 0; o >>= 1) ssum += __shfl_xor(ssum, o);
        float ar = (w < nv) ? (e / ssum) * srs[p] : 0.f;
        sar[n][w] = ar;
        float t2 = (w < nv) ? ar * smu[p] : 0.f;
        for (int o = 32; o > 0; o >>= 1) t2 += __shfl_xor(t2, o);
        if (lane == 0) s2red[n] = t2;
    }
    __syncthreads();

    // ---- combine per-row weights across (<=2) covering windows ----
    if (tid < Pp) {
        int p = tid;
        int na = (p >> 5) - 1, nb = (p >> 5);
        float wt = 0.f;
        if (na >= 0 && na <= 3) wt += sar[na][p - na * Ss];
        if (nb <= 3)            wt += sar[nb][p - nb * Ss];
        swt[p] = wt;
    }
    if (tid == 0) soff = 0.25f * (s2red[0] + s2red[1] + s2red[2] + s2red[3]);
    __syncthreads();

    // ---- pass 2: combined weighted feature sum (cache-warm re-read) ----
    {
        int g = tid >> 7, c4 = tid & 127;
        const float4* f4 = (const float4*)fbase;
        float4 acc = make_float4(0.f, 0.f, 0.f, 0.f);
#pragma unroll 4
        for (int p = g; p < Pp; p += 4) {
            float wt = swt[p];
            float4 v = f4[p * 128 + c4];
            acc.x = fmaf(wt, v.x, acc.x);
            acc.y = fmaf(wt, v.y, acc.y);
            acc.z = fmaf(wt, v.z, acc.z);
            acc.w = fmaf(wt, v.w, acc.w);
        }
        *(float4*)&spart[g][c4 * 4] = acc;
    }
    __syncthreads();
    {
        float v = spart[0][tid] + spart[1][tid] + spart[2][tid] + spart[3][tid];
        fmean[(size_t)bx * Dd + tid] = 0.25f * v - soff;
    }
}

// ---------------------------------------------------------------------------
extern "C" void kernel_launch(void* const* d_in, const int* in_sizes, int n_in,
                              void* d_out, int out_size, void* d_ws, size_t ws_size,
                              hipStream_t stream) {
    const float* feats  = (const float*)d_in[0];
    const float* coords = (const float*)d_in[1];
    // d_in[2] = mask, unused (all false, and unused by the reference body)
    const float* z  = (const float*)d_in[3];
    const float* Wq = (const float*)d_in[4];
    const float* Wk = (const float*)d_in[5];
    const float* Wv = (const float*)d_in[6];
    const float* W1 = (const float*)d_in[7];
    const float* b1 = (const float*)d_in[8];
    const float* W2 = (const float*)d_in[9];
    const float* b2 = (const float*)d_in[10];
    const float* Wo = (const float*)d_in[11];
    const float* bo = (const float*)d_in[12];
    float* out = (float*)d_out;

    // workspace layout (floats)
    float* ws = (float*)d_ws;
    float*  cstats = ws;                        // 16
    float*  zbase  = ws + 16;                   // zero-init region:
    float*  Q      = zbase;                     // 64*512
    float*  QK     = Q + Ll * Dd;               // 64*512
    float*  G      = QK + Ll * Dd;              // 64*512
    float*  sqk    = G + Ll * Dd;               // 64
    float*  qb2    = sqk + Ll;                  // 64
    float*  zl     = qb2 + Ll;                  // 256*512
    const int nzero = 3 * Ll * Dd + 2 * Ll + Bz * Ll * Dd;  // 229504
    float*  fmean  = zbase + nzero;             // 256*512 (written directly, no init)

    init_k<<<(nzero + 255) / 256, 256, 0, stream>>>(zbase, nzero, out, bo);
    coordstats_k<<<Bz, 1024, 0, stream>>>(coords, cstats);

    // Q = z @ Wq^T (split-K); epilogue: qb2[l] = sum_e Q[l,e]*b2[e]
    gemmsk<1><<<dim3(Dd / 32, Ll / 64, 8), 256, 0, stream>>>(
        z, Wq, Q, nullptr, nullptr, b2, qb2, Dd, Dd, 8);
    // QK = Q @ Wk and G = Q @ W2 fused; epilogue: sqk[l] = sum_d QK[l,d]
    gemmsk<0><<<dim3(Dd / 32, Ll / 64, 16), 256, 0, stream>>>(
        Q, Wk, QK, W2, G, nullptr, sqk, Dd, Dd, 8);

    attn2<<<Bz * Ll, 512, 0, stream>>>(feats, coords, cstats,
                                       QK, G, sqk, qb2, W1, b1, fmean);

    // zl = fmean @ Wv^T ; out = bias + zl @ Wo^T
    gemmsk<1><<<dim3(Dd / 32, (Bz * Ll) / 64, 8), 256, 0, stream>>>(
        fmean, Wv, zl, nullptr, nullptr, nullptr, nullptr, Dd, Dd, 8);
    gemmsk<1><<<dim3(Dd / 32, (Bz * Ll) / 64, 8), 256, 0, stream>>>(
        zl, Wo, out, nullptr, nullptr, nullptr, nullptr, Dd, Dd, 8);
}